// Round 3
// baseline (461.233 us; speedup 1.0000x reference)
//
#include <hip/hip_runtime.h>

typedef short s8v  __attribute__((ext_vector_type(8)));
typedef float f4v  __attribute__((ext_vector_type(4)));
typedef int   v4i  __attribute__((ext_vector_type(4)));
typedef float v4f  __attribute__((ext_vector_type(4)));
typedef int   v2i  __attribute__((ext_vector_type(2)));

#define NNODES 8192
#define FDIM   256
#define NJC    4          // j-chunks (split-K factor)
#define JLEN   2048       // columns-j per chunk
#define TROWS  32         // rows per block (R12: 64->32 -> 1024 blocks = 4/CU, acc halves)
#define KSTEP  32         // k per step = one PB k-tile
#define NSTEP  64         // JLEN / KSTEP

__device__ __forceinline__ float bf2f(unsigned short u) {
    unsigned int x = ((unsigned int)u) << 16;
    return __builtin_bit_cast(float, x);
}
__device__ __forceinline__ unsigned short f2bf(float f) {
    unsigned int x = __builtin_bit_cast(unsigned int, f);
    x += 0x7fffu + ((x >> 16) & 1u);
    return (unsigned short)(x >> 16);
}
// RTNE pack of 2 f32 -> 1 dword of 2 bf16
__device__ __forceinline__ int cvt_pk(float lo, float hi) {
    int r;
    asm("v_cvt_pk_bf16_f32 %0, %1, %2" : "=v"(r) : "v"(lo), "v"(hi));
    return r;
}

// Barrier WITHOUT vmcnt drain (R11): LDS visibility needs only lgkmcnt(0);
// vmem data-deps are compiler-waited. Keeps adj prefetch in flight.
__device__ __forceinline__ void barrier_lds_only() {
    asm volatile("s_waitcnt lgkmcnt(0)" ::: "memory");
    __builtin_amdgcn_s_barrier();
    asm volatile("" ::: "memory");
}

// ---------------- Kernel 0: fused WT + wv ----------------
__global__ __launch_bounds__(256) void prep_kernel(const float* __restrict__ W,
                                                   const float* __restrict__ a,
                                                   unsigned short* __restrict__ WT,
                                                   float* __restrict__ v1,
                                                   float* __restrict__ v2) {
    if (blockIdx.x < 256) {
        int idx = blockIdx.x * 256 + threadIdx.x;
        int r = idx >> 8, c = idx & 255;
        WT[c * 256 + r] = f2bf(W[r * 256 + c]);
    } else {
        __shared__ float r1[256], r2[256];
        int b = blockIdx.x - 256, n = threadIdx.x;
        float w = W[(size_t)b * FDIM + n];
        r1[n] = w * a[n];
        r2[n] = w * a[FDIM + n];
        __syncthreads();
        for (int off = 128; off > 0; off >>= 1) {
            if (n < off) { r1[n] += r1[n + off]; r2[n] += r2[n + off]; }
            __syncthreads();
        }
        if (n == 0) { v1[b] = r1[0]; v2[b] = r2[0]; }
    }
}

// ---------------- Kernel 1: PB = tiled bf16 Wh; s1/s2 = h@v (fp32) ----------------
// R12: grid 128->256 (32 rows/block, 2 waves) -- was using half the CUs.
__global__ __launch_bounds__(128) void wh_kernel(
    const float* __restrict__ h, const unsigned short* __restrict__ WT,
    const float* __restrict__ v1, const float* __restrict__ v2,
    unsigned short* __restrict__ PB,
    float* __restrict__ s1, float* __restrict__ s2)
{
    __shared__ float v1_lds[FDIM], v2_lds[FDIM];
    int tid = threadIdx.x;
    v1_lds[tid] = v1[tid];       v1_lds[tid + 128] = v1[tid + 128];
    v2_lds[tid] = v2[tid];       v2_lds[tid + 128] = v2[tid + 128];
    __syncthreads();

    int w = tid >> 6, lane = tid & 63, q = lane >> 4, l15 = lane & 15;
    int i_base = blockIdx.x * 32 + w * 16;

    f4v acc[16] = {};
    float s1p = 0.f, s2p = 0.f;

    for (int k0 = 0; k0 < 256; k0 += 32) {
        const float* hp = h + (size_t)(i_base + l15) * FDIM + k0 + q * 8;
        f4v h0 = *(const f4v*)hp;
        f4v h1 = *(const f4v*)(hp + 4);
        union { v4i u; s8v s; } af;
        af.u[0] = cvt_pk(h0[0], h0[1]);
        af.u[1] = cvt_pk(h0[2], h0[3]);
        af.u[2] = cvt_pk(h1[0], h1[1]);
        af.u[3] = cvt_pk(h1[2], h1[3]);
#pragma unroll
        for (int j = 0; j < 4; ++j) {
            s1p += h0[j] * v1_lds[k0 + q * 8 + j] + h1[j] * v1_lds[k0 + q * 8 + 4 + j];
            s2p += h0[j] * v2_lds[k0 + q * 8 + j] + h1[j] * v2_lds[k0 + q * 8 + 4 + j];
        }
#pragma unroll
        for (int t = 0; t < 16; ++t) {
            s8v bf = *(const s8v*)(WT + (size_t)(t * 16 + l15) * FDIM + k0 + q * 8);
            acc[t] = __builtin_amdgcn_mfma_f32_16x16x32_bf16(af.s, bf, acc[t], 0, 0, 0);
        }
    }

    s1p += __shfl_xor(s1p, 16, 64);
    s1p += __shfl_xor(s1p, 32, 64);
    s2p += __shfl_xor(s2p, 16, 64);
    s2p += __shfl_xor(s2p, 32, 64);
    if (lane < 16) {
        s1[i_base + lane] = s1p;
        s2[i_base + lane] = s2p;
    }

#pragma unroll
    for (int t = 0; t < 16; ++t) {
        int i0 = i_base + q * 4;
        size_t a16 = (size_t)((i0 >> 5) * 16 + t) * 512
                   + l15 * 32 + ((i0 >> 3) & 3) * 8 + (i0 & 7);
        v2i pk;
        pk[0] = cvt_pk(acc[t][0], acc[t][1]);
        pk[1] = cvt_pk(acc[t][2], acc[t][3]);
        *(v2i*)(PB + a16) = pk;
    }
}

// ---------------- Kernel 2: split-K partial attention ----------------
// R12 structure: grid 1024 = 256 rt x 4 jc (jc = bid&3 pins one 1-MiB PB
// slice per XCD under round-robin dispatch), 4 blocks/CU (16 waves/CU).
// Block: 32 rows x 256 cols, 64 steps of k=32. adj prefetched 3+ steps deep
// in registers; in-loop barriers are lgkmcnt-only so prefetch stays in
// flight (T4). P_lds: k-major [k/8][row] x 8 shorts, 32B XOR swizzle;
// writer 8B / reader 16B verified conflict-free + bijective.
__global__ __launch_bounds__(256, 4) void attn_partial(
    const int* __restrict__ adj, const unsigned short* __restrict__ PB,
    const float* __restrict__ s1, const float* __restrict__ s2,
    float* __restrict__ Npart, float* __restrict__ dpart)
{
    __shared__ float s2_lds[JLEN];                      // 8 KB
    __shared__ unsigned short P_lds[2][TROWS * KSTEP];  // 2 x 2 KB
    __shared__ float dsum_lds[TROWS][8];                // 1 KB

    int tid = threadIdx.x;
    int jc = blockIdx.x & 3, rt = blockIdx.x >> 2;
    int j0 = jc * JLEN;

    for (int i = tid; i < JLEN / 4; i += 256)
        ((v4f*)s2_lds)[i] = ((const v4f*)(s2 + j0))[i];

    // P-generator role: row m 0..31, k-slice idx 0..7, 4 j's per thread/step
    int m = tid >> 3, idx = tid & 7;
    int row_g = rt * TROWS + m;
    float s1v = s1[row_g];
    const int* arow = adj + (size_t)row_g * NNODES + j0 + idx * 4;
    // write addr (shorts): ((q_w*32+m)*8 + half*4) ^ (q_w*16)
    int q_w = idx >> 1, half = idx & 1;
    int woff = (((q_w * 32 + m) * 8 + half * 4)) ^ (q_w * 16);

    // MFMA role: wave g -> cols g*64 + t*16 + l15; rowhalves rh=0..1
    int g = tid >> 6, lane = tid & 63, q = lane >> 4, l15 = lane & 15;
    const unsigned short* pbb = PB + (size_t)(jc * 64) * 16 * 512 + l15 * 32 + q * 8;

    f4v acc[2][4] = {};
    float dsum = 0.0f;

    __syncthreads();  // s2 staged (full drain once is fine)

    // prologue: adj[0] for P0; adj[1..3] parked (3.3 steps of slack)
    v4i p0 = __builtin_nontemporal_load((const v4i*)(arow));
    v4i a1 = __builtin_nontemporal_load((const v4i*)(arow + 1 * KSTEP));
    v4i a2 = __builtin_nontemporal_load((const v4i*)(arow + 2 * KSTEP));
    v4i a3 = __builtin_nontemporal_load((const v4i*)(arow + 3 * KSTEP));
    {
        v4f sv = *(const v4f*)&s2_lds[idx * 4];
        float pa[4];
#pragma unroll
        for (int j = 0; j < 4; ++j) {
            float x = s1v + sv[j];
            float p = (p0[j] > 0) ? __expf(fmaxf(x, 0.2f * x)) : 0.0f;
            pa[j] = p; dsum += p;
        }
        v2i pv;
        pv[0] = cvt_pk(pa[0], pa[1]);
        pv[1] = cvt_pk(pa[2], pa[3]);
        *(v2i*)&P_lds[0][woff] = pv;
    }
    barrier_lds_only();

    for (int s = 0; s < NSTEP; ++s) {
        // adj for step s+4 (stays in flight across lgkm-only barriers)
        int kn = (s < NSTEP - 4) ? (s + 4) * KSTEP : 0;
        v4i nx = __builtin_nontemporal_load((const v4i*)(arow + kn));

        // B-frags for step s: contiguous 1 KiB per wave, reused over 2 rh
        s8v bf[4];
#pragma unroll
        for (int t = 0; t < 4; ++t)
            bf[t] = *(const s8v*)(pbb + (size_t)(s * 16 + g * 4 + t) * 512);

        // P for step s+1 from a1 (loaded 3 iterations ago)
        if (s < NSTEP - 1) {
            v4f sv = *(const v4f*)&s2_lds[(s + 1) * KSTEP + idx * 4];
            float pa[4];
#pragma unroll
            for (int j = 0; j < 4; ++j) {
                float x = s1v + sv[j];
                float p = (a1[j] > 0) ? __expf(fmaxf(x, 0.2f * x)) : 0.0f;
                pa[j] = p; dsum += p;
            }
            v2i pv;
            pv[0] = cvt_pk(pa[0], pa[1]);
            pv[1] = cvt_pk(pa[2], pa[3]);
            *(v2i*)&P_lds[(s + 1) & 1][woff] = pv;
        }

        // MFMA over 2 rowhalves
        const unsigned short* pbuf = P_lds[s & 1];
#pragma unroll
        for (int rh = 0; rh < 2; ++rh) {
            s8v af = *(const s8v*)&pbuf[((q * 32 + rh * 16 + l15) * 8) ^ (q * 16)];
#pragma unroll
            for (int t = 0; t < 4; ++t)
                acc[rh][t] = __builtin_amdgcn_mfma_f32_16x16x32_bf16(af, bf[t], acc[rh][t], 0, 0, 0);
        }

        barrier_lds_only();
        a1 = a2; a2 = a3; a3 = nx;
    }

    // partial denominator
    dsum_lds[m][idx] = dsum;
    __syncthreads();
    if (tid < TROWS) {
        float d = 0.f;
#pragma unroll
        for (int k = 0; k < 8; ++k) d += dsum_lds[tid][k];
        dpart[jc * NNODES + rt * TROWS + tid] = d;
    }

    // partial numerator: row = rh*16 + q*4 + r, col = g*64 + t*16 + l15
#pragma unroll
    for (int rh = 0; rh < 2; ++rh)
#pragma unroll
        for (int r = 0; r < 4; ++r) {
            int row = rh * 16 + q * 4 + r;
            float* base = Npart + ((size_t)(jc * NNODES) + rt * TROWS + row) * FDIM;
#pragma unroll
            for (int t = 0; t < 4; ++t)
                __builtin_nontemporal_store(acc[rh][t][r], base + g * 64 + t * 16 + l15);
        }
}

// ---------------- Kernel 3: reduce partials, normalize ----------------
__global__ __launch_bounds__(256) void reduce_kernel(
    const float* __restrict__ Npart, const float* __restrict__ dpart,
    float* __restrict__ out)
{
    int i = blockIdx.x, n = threadIdx.x;
    float d = 0.f, acc = 0.f;
#pragma unroll
    for (int jc = 0; jc < NJC; ++jc) {
        d += dpart[jc * NNODES + i];
        acc += Npart[((size_t)(jc * NNODES) + i) * FDIM + n];
    }
    out[(size_t)i * FDIM + n] = acc / fmaxf(d, 1e-30f);
}

extern "C" void kernel_launch(void* const* d_in, const int* in_sizes, int n_in,
                              void* d_out, int out_size, void* d_ws, size_t ws_size,
                              hipStream_t stream) {
    const float* h   = (const float*)d_in[0];
    const int*   adj = (const int*)d_in[1];
    const float* W   = (const float*)d_in[2];
    const float* a   = (const float*)d_in[3];
    float* out = (float*)d_out;

    char* ws = (char*)d_ws;
    unsigned short* PB = (unsigned short*)ws;                  // 4 MiB (tiled Wh)
    float* s1 = (float*)(ws + (4u << 20));                     // 32 KiB
    float* s2 = (float*)(ws + (4u << 20) + (32u << 10));       // 32 KiB
    unsigned short* WT = (unsigned short*)(ws + (4u << 20) + (64u << 10));   // 128 KiB
    float* v1 = (float*)(ws + (4u << 20) + (192u << 10));      // 1 KiB
    float* v2 = (float*)(ws + (4u << 20) + (193u << 10));      // 1 KiB
    float* dpart = (float*)(ws + (5u << 20));                  // 128 KiB
    float* Npart = (float*)(ws + (8u << 20));                  // 32 MiB

    hipLaunchKernelGGL(prep_kernel, dim3(512), dim3(256), 0, stream, W, a, WT, v1, v2);
    hipLaunchKernelGGL(wh_kernel, dim3(256), dim3(128), 0, stream, h, WT, v1, v2, PB, s1, s2);
    hipLaunchKernelGGL(attn_partial, dim3(256 * NJC), dim3(256), 0, stream,
                       adj, PB, s1, s2, Npart, dpart);
    hipLaunchKernelGGL(reduce_kernel, dim3(NNODES), dim3(256), 0, stream, Npart, dpart, out);
}